// Round 1
// baseline (165.695 us; speedup 1.0000x reference)
//
#include <hip/hip_runtime.h>
#include <hip/hip_bf16.h>
#include <math.h>

#define NB 32
#define TB 128
#define IB 128
constexpr float CLAMP_MAX = 20.0f;

__global__ void init_ws_kernel(float* ws) {
    ws[0] = 0.0f;   // sum of bpr over valid rows
    ws[1] = 0.0f;   // count of valid rows
}

__global__ __launch_bounds__(256) void bpr_row_kernel(
        const float* __restrict__ input,
        const float* __restrict__ target,
        float* __restrict__ ws) {
    const int row = blockIdx.x;              // 0 .. N*T-1
    const float* in = input  + (size_t)row * IB;
    const float* tg = target + (size_t)row * IB;

    __shared__ float negV[IB];
    __shared__ float posV[IB];
    __shared__ int   cnts[3];                // negC, posC, validC
    __shared__ float wredu[4];

    const int tid = threadIdx.x;
    if (tid == 0) { cnts[0] = 0; cnts[1] = 0; cnts[2] = 0; }
    __syncthreads();

    if (tid < IB) {
        float t = tg[tid];
        if (!(t != t)) {                     // non-NaN label
            atomicAdd(&cnts[2], 1);
            float x  = in[tid];
            float nt = t * 2.0f - 1.0f;
            if (nt > 0.0f) {
                int p = atomicAdd(&cnts[1], 1);
                posV[p] = x;
            } else if (nt < 0.0f) {
                int p = atomicAdd(&cnts[0], 1);
                negV[p] = x;
            }
        }
    }
    __syncthreads();

    const int negC   = cnts[0];
    const int posC   = cnts[1];
    const int validC = cnts[2];
    const int total  = negC * posC;

    float acc = 0.0f;
    for (int p = tid; p < total; p += 256) {
        int i = p / posC;                    // posC > 0 whenever total > 0
        int j = p - i * posC;
        float d = negV[i] - posV[j];
        d = fminf(d, CLAMP_MAX);
        acc += log1pf(__expf(d));
    }

    // block reduction: wave64 shuffle then across 4 waves via LDS
    #pragma unroll
    for (int off = 32; off > 0; off >>= 1)
        acc += __shfl_down(acc, off, 64);
    if ((tid & 63) == 0) wredu[tid >> 6] = acc;
    __syncthreads();
    if (tid == 0) {
        if (validC > 0) {
            float s = wredu[0] + wredu[1] + wredu[2] + wredu[3];
            atomicAdd(&ws[0], s);
            atomicAdd(&ws[1], 1.0f);
        }
    }
}

__global__ void finalize_kernel(const float* __restrict__ ws, float* __restrict__ out) {
    out[0] = ws[0] / ws[1];
}

extern "C" void kernel_launch(void* const* d_in, const int* in_sizes, int n_in,
                              void* d_out, int out_size, void* d_ws, size_t ws_size,
                              hipStream_t stream) {
    const float* input  = (const float*)d_in[0];
    const float* target = (const float*)d_in[1];
    float* out = (float*)d_out;
    float* ws  = (float*)d_ws;

    hipLaunchKernelGGL(init_ws_kernel, dim3(1), dim3(1), 0, stream, ws);
    hipLaunchKernelGGL(bpr_row_kernel, dim3(NB * TB), dim3(256), 0, stream,
                       input, target, ws);
    hipLaunchKernelGGL(finalize_kernel, dim3(1), dim3(1), 0, stream, ws, out);
}

// Round 2
// 68.748 us; speedup vs baseline: 2.4102x; 2.4102x over previous
//
#include <hip/hip_runtime.h>
#include <hip/hip_bf16.h>
#include <math.h>

#define NB 32
#define TB 128
#define IB 128
#define ROWS (NB * TB)
constexpr float CLAMP_MAX = 20.0f;
constexpr float LOG2E = 1.4426950408889634f;
constexpr float LN2   = 0.6931471805599453f;

// Kernel 1: one block per row. Compact pos/neg item values into LDS, then
// wave-per-negative / lane-per-positive pair sweep. Writes per-row partials
// to workspace (NO global atomics -- that was the 112us serialization).
__global__ __launch_bounds__(256) void bpr_row_kernel(
        const float* __restrict__ input,
        const float* __restrict__ target,
        float* __restrict__ sums,     // [ROWS]
        float* __restrict__ valid) {  // [ROWS]
    const int row = blockIdx.x;
    const float* in = input  + (size_t)row * IB;
    const float* tg = target + (size_t)row * IB;

    __shared__ float negV[IB];
    __shared__ float posV[IB];
    __shared__ int   cnts[2];         // negC, posC
    __shared__ float wredu[4];

    const int tid  = threadIdx.x;
    const int wave = tid >> 6;
    const int lane = tid & 63;

    if (tid < 2) cnts[tid] = 0;
    __syncthreads();

    if (tid < IB) {
        float t = tg[tid];
        if (t == t) {                  // non-NaN; t is exactly 0.0 or 1.0
            float x = in[tid];
            if (t > 0.5f) { int p = atomicAdd(&cnts[1], 1); posV[p] = x; }
            else          { int p = atomicAdd(&cnts[0], 1); negV[p] = x; }
        }
    }
    __syncthreads();

    const int negC = cnts[0];
    const int posC = cnts[1];

    float acc = 0.0f;
    for (int i = wave; i < negC; i += 4) {
        const float nv = negV[i];      // wave-uniform -> LDS broadcast
        for (int j = lane; j < posC; j += 64) {
            float d = fminf(nv - posV[j], CLAMP_MAX);
            // softplus(d) = ln(1 + e^d) = log2(1 + 2^(d*log2e)) * ln2
            float e = __builtin_amdgcn_exp2f(d * LOG2E);
            acc += __builtin_amdgcn_logf(1.0f + e) * LN2;
        }
    }

    // block reduction: wave64 shuffle, then 4 partials via LDS
    #pragma unroll
    for (int off = 32; off > 0; off >>= 1)
        acc += __shfl_down(acc, off, 64);
    if (lane == 0) wredu[wave] = acc;
    __syncthreads();
    if (tid == 0) {
        const bool v = (negC + posC) > 0;   // binary labels: valid <=> pos|neg exists
        sums[row]  = v ? (wredu[0] + wredu[1] + wredu[2] + wredu[3]) : 0.0f;
        valid[row] = v ? 1.0f : 0.0f;
    }
}

// Kernel 2: single block reduces the 4096 per-row partials and divides.
__global__ __launch_bounds__(256) void bpr_reduce_kernel(
        const float* __restrict__ sums,
        const float* __restrict__ valid,
        float* __restrict__ out) {
    const int tid  = threadIdx.x;
    const int wave = tid >> 6;
    const int lane = tid & 63;
    float s = 0.0f, c = 0.0f;
    for (int i = tid; i < ROWS; i += 256) {
        s += sums[i];
        c += valid[i];
    }
    #pragma unroll
    for (int off = 32; off > 0; off >>= 1) {
        s += __shfl_down(s, off, 64);
        c += __shfl_down(c, off, 64);
    }
    __shared__ float ss[4], cc[4];
    if (lane == 0) { ss[wave] = s; cc[wave] = c; }
    __syncthreads();
    if (tid == 0) {
        float S = ss[0] + ss[1] + ss[2] + ss[3];
        float C = cc[0] + cc[1] + cc[2] + cc[3];
        out[0] = S / C;
    }
}

extern "C" void kernel_launch(void* const* d_in, const int* in_sizes, int n_in,
                              void* d_out, int out_size, void* d_ws, size_t ws_size,
                              hipStream_t stream) {
    const float* input  = (const float*)d_in[0];
    const float* target = (const float*)d_in[1];
    float* out   = (float*)d_out;
    float* sums  = (float*)d_ws;
    float* valid = sums + ROWS;

    hipLaunchKernelGGL(bpr_row_kernel, dim3(ROWS), dim3(256), 0, stream,
                       input, target, sums, valid);
    hipLaunchKernelGGL(bpr_reduce_kernel, dim3(1), dim3(256), 0, stream,
                       sums, valid, out);
}

// Round 3
// 66.164 us; speedup vs baseline: 2.5043x; 1.0391x over previous
//
#include <hip/hip_runtime.h>
#include <hip/hip_bf16.h>
#include <math.h>

#define NB 32
#define TB 128
#define IB 128
#define ROWS (NB * TB)
#define WPB 4   // rows (waves) per block
constexpr float CLAMP_MAX = 20.0f;
constexpr float LOG2E = 1.4426950408889634f;
constexpr float LN2   = 0.6931471805599453f;

__device__ __forceinline__ float softplus_clamped(float d) {
    d = fminf(d, CLAMP_MAX);
    // softplus(d) = ln(1 + e^d) = log2(1 + 2^(d*log2e)) * ln2
    float e = __builtin_amdgcn_exp2f(d * LOG2E);
    return __builtin_amdgcn_logf(1.0f + e) * LN2;
}

// One row per WAVE. No atomics, no __syncthreads: ballot/popc prefix
// compaction into a wave-private LDS slice, then neg x pos pair sweep.
__global__ __launch_bounds__(256) void bpr_row_kernel(
        const float* __restrict__ input,
        const float* __restrict__ target,
        float* __restrict__ sums,     // [ROWS]
        float* __restrict__ valid) {  // [ROWS]
    __shared__ float negQ[WPB][IB];
    __shared__ float posQ[WPB][IB];

    const int tid  = threadIdx.x;
    const int wave = tid >> 6;
    const int lane = tid & 63;
    const int row  = blockIdx.x * WPB + wave;

    const float2 x2 = ((const float2*)(input  + (size_t)row * IB))[lane];
    const float2 t2 = ((const float2*)(target + (size_t)row * IB))[lane];

    // NaN compares false in both: NaN labels are neither pos nor neg.
    const bool p0 = t2.x > 0.5f, p1 = t2.y > 0.5f;
    const bool n0 = t2.x < 0.5f, n1 = t2.y < 0.5f;

    const unsigned long long pm0 = __ballot(p0), pm1 = __ballot(p1);
    const unsigned long long nm0 = __ballot(n0), nm1 = __ballot(n1);
    const unsigned long long lt  = (1ULL << lane) - 1ULL;

    const int posC = __popcll(pm0) + __popcll(pm1);
    const int negC = __popcll(nm0) + __popcll(nm1);

    float* nq = negQ[wave];
    float* pq = posQ[wave];
    if (n0) nq[__popcll(nm0 & lt)] = x2.x;
    if (n1) nq[__popcll(nm0) + __popcll(nm1 & lt)] = x2.y;
    if (p0) pq[__popcll(pm0 & lt)] = x2.x;
    if (p1) pq[__popcll(pm0) + __popcll(pm1 & lt)] = x2.y;
    // wave-private slice: in-wave lgkmcnt ordering suffices, no barrier

    float acc = 0.0f;
    int i = 0;
    for (; i + 4 <= negC; i += 4) {
        const float a0 = nq[i], a1 = nq[i+1], a2 = nq[i+2], a3 = nq[i+3];
        for (int j = lane; j < posC; j += 64) {
            const float pv = pq[j];
            acc += softplus_clamped(a0 - pv);
            acc += softplus_clamped(a1 - pv);
            acc += softplus_clamped(a2 - pv);
            acc += softplus_clamped(a3 - pv);
        }
    }
    for (; i < negC; ++i) {
        const float a0 = nq[i];
        for (int j = lane; j < posC; j += 64)
            acc += softplus_clamped(a0 - pq[j]);
    }

    #pragma unroll
    for (int off = 32; off > 0; off >>= 1)
        acc += __shfl_down(acc, off, 64);
    if (lane == 0) {
        const bool v = (negC + posC) > 0;   // binary labels: valid <=> any non-NaN
        sums[row]  = v ? acc : 0.0f;
        valid[row] = v ? 1.0f : 0.0f;
    }
}

// Single block reduces the 4096 per-row partials and divides.
__global__ __launch_bounds__(256) void bpr_reduce_kernel(
        const float* __restrict__ sums,
        const float* __restrict__ valid,
        float* __restrict__ out) {
    const int tid  = threadIdx.x;
    const int wave = tid >> 6;
    const int lane = tid & 63;
    float s = 0.0f, c = 0.0f;
    for (int i = tid; i < ROWS; i += 256) {
        s += sums[i];
        c += valid[i];
    }
    #pragma unroll
    for (int off = 32; off > 0; off >>= 1) {
        s += __shfl_down(s, off, 64);
        c += __shfl_down(c, off, 64);
    }
    __shared__ float ss[4], cc[4];
    if (lane == 0) { ss[wave] = s; cc[wave] = c; }
    __syncthreads();
    if (tid == 0) {
        float S = ss[0] + ss[1] + ss[2] + ss[3];
        float C = cc[0] + cc[1] + cc[2] + cc[3];
        out[0] = S / C;
    }
}

extern "C" void kernel_launch(void* const* d_in, const int* in_sizes, int n_in,
                              void* d_out, int out_size, void* d_ws, size_t ws_size,
                              hipStream_t stream) {
    const float* input  = (const float*)d_in[0];
    const float* target = (const float*)d_in[1];
    float* out   = (float*)d_out;
    float* sums  = (float*)d_ws;
    float* valid = sums + ROWS;

    hipLaunchKernelGGL(bpr_row_kernel, dim3(ROWS / WPB), dim3(256), 0, stream,
                       input, target, sums, valid);
    hipLaunchKernelGGL(bpr_reduce_kernel, dim3(1), dim3(256), 0, stream,
                       sums, valid, out);
}